// Round 1
// baseline (731.721 us; speedup 1.0000x reference)
//
#include <hip/hip_runtime.h>
#include <math.h>

// irreps: (256,1)@0, (256,3)@256, (128,5)@1024, (64,7)@1664 ; DIM=2112, OUT=704
#define ROW_DIM 2112
#define OUT_DIM 704
#define BLOCK 256

__global__ __launch_bounds__(BLOCK) void slownorm_kernel(
    const float* __restrict__ in, float* __restrict__ out)
{
    __shared__ float row[ROW_DIM];  // 8448 B

    const int b = blockIdx.x;
    const float* __restrict__ src = in + (size_t)b * ROW_DIM;

    // Coalesced vector load of the whole row into LDS: 528 float4.
    const float4* __restrict__ src4 = (const float4*)src;
    float4* row4 = (float4*)row;
    #pragma unroll
    for (int i = threadIdx.x; i < ROW_DIM / 4; i += BLOCK) {
        row4[i] = src4[i];
    }
    __syncthreads();

    float* __restrict__ dst = out + (size_t)b * OUT_DIM;

    // 704 outputs, 256 threads -> iterations at o = t, t+256, t+512.
    for (int o = threadIdx.x; o < OUT_DIM; o += BLOCK) {
        int off, d, idx;
        if (o < 256)      { d = 1; off = 0;    idx = o;       }
        else if (o < 512) { d = 3; off = 256;  idx = o - 256; }
        else if (o < 640) { d = 5; off = 1024; idx = o - 512; }
        else              { d = 7; off = 1664; idx = o - 640; }

        const float* p = row + off + idx * d;
        float s = 0.0f;
        #pragma unroll 7
        for (int k = 0; k < d; ++k) s += p[k] * p[k];
        dst[o] = sqrtf(s);
    }
}

extern "C" void kernel_launch(void* const* d_in, const int* in_sizes, int n_in,
                              void* d_out, int out_size, void* d_ws, size_t ws_size,
                              hipStream_t stream)
{
    const float* features = (const float*)d_in[0];
    float* out = (float*)d_out;
    const int batch = in_sizes[0] / ROW_DIM;  // 65536
    slownorm_kernel<<<batch, BLOCK, 0, stream>>>(features, out);
}